// Round 7
// baseline (58.459 us; speedup 1.0000x reference)
//
#include <hip/hip_runtime.h>

typedef __attribute__((ext_vector_type(8))) int   i32x8;
typedef __attribute__((ext_vector_type(4))) float f32x4;
typedef unsigned int uint32;

constexpr int N = 16384;
constexpr int K = 1024;
constexpr int M = 1024;

#define WAITVM(n) asm volatile("s_waitcnt vmcnt(" #n ")" ::: "memory")
#define FENCE() asm volatile("" ::: "memory")
#define BAR()                          \
    do {                               \
        FENCE();                       \
        __builtin_amdgcn_s_barrier();  \
        FENCE();                       \
    } while (0)

__device__ inline void gload_lds16(const unsigned char* g, unsigned char* l) {
    __builtin_amdgcn_global_load_lds(
        (const __attribute__((address_space(1))) unsigned int*)g,
        (__attribute__((address_space(3))) unsigned int*)l,
        16, 0, 0);
}

// pack 4 f32 -> 4 OCP e4m3 bytes (k-ascending), saturating
__device__ inline uint32 pack4_fp8(float a, float b, float c, float d) {
    int v = __builtin_amdgcn_cvt_pk_fp8_f32(a, b, 0, false);   // bytes 0,1
    v = __builtin_amdgcn_cvt_pk_fp8_f32(c, d, v, true);        // bytes 2,3
    return (uint32)v;
}

// One block per mu row: norm; W8 = mu_n*inv_std*0.25 (fp8); mmh = -0.5*sum(mu_n^2*inv_std)
__global__ void prep_mu(const float* __restrict__ mu, const float* __restrict__ stdv,
                        uint32* __restrict__ Wb8, float* __restrict__ mmh) {
    int m = blockIdx.x;
    int t = threadIdx.x;
    float4 v = ((const float4*)(mu + (size_t)m * K))[t];
    float4 s = ((const float4*)stdv)[t];
    float ix = 1.0f / s.x, iy = 1.0f / s.y, iz = 1.0f / s.z, iw = 1.0f / s.w;
    float sum2  = v.x * v.x + v.y * v.y + v.z * v.z + v.w * v.w;
    float sum2w = v.x * v.x * ix + v.y * v.y * iy + v.z * v.z * iz + v.w * v.w * iw;
    for (int off = 32; off > 0; off >>= 1) {
        sum2  += __shfl_down(sum2, off, 64);
        sum2w += __shfl_down(sum2w, off, 64);
    }
    __shared__ float r2[4], r2w[4];
    __shared__ float s_scale;
    int lane = t & 63, w = t >> 6;
    if (lane == 0) { r2[w] = sum2; r2w[w] = sum2w; }
    __syncthreads();
    if (t == 0) {
        float tot2  = r2[0] + r2[1] + r2[2] + r2[3];
        float tot2w = r2w[0] + r2w[1] + r2w[2] + r2w[3];
        mmh[m] = -0.5f * tot2w / tot2;
        s_scale = rsqrtf(tot2) * 0.25f;        // fold the 1/4 fp8-range scale
    }
    __syncthreads();
    float sc = s_scale;
    Wb8[m * (K / 4) + t] = pack4_fp8(v.x * ix * sc, v.y * iy * sc,
                                     v.z * iz * sc, v.w * iw * sc);
}

// Wave-per-row: x->fp8, xxh = -0.5*sum(x^2*inv_std). No barriers, no LDS.
__global__ __launch_bounds__(256) void prep_x(const float* __restrict__ x,
                                              const float* __restrict__ stdv,
                                              uint32* __restrict__ xb8,
                                              float* __restrict__ xxh) {
    int row = blockIdx.x * 4 + (threadIdx.x >> 6);
    int lane = threadIdx.x & 63;
    const float4* src = (const float4*)(x + (size_t)row * K);
    const float4* sp  = (const float4*)stdv;
    uint32* dst = xb8 + (size_t)row * (K / 4);
    float ssum = 0.f;
#pragma unroll
    for (int i = 0; i < 4; ++i) {
        int idx = lane + 64 * i;
        float4 v = src[idx];
        float4 s = sp[idx];
        ssum += v.x * v.x / s.x + v.y * v.y / s.y + v.z * v.z / s.z + v.w * v.w / s.w;
        dst[idx] = pack4_fp8(v.x, v.y, v.z, v.w);
    }
#pragma unroll
    for (int off = 32; off > 0; off >>= 1) ssum += __shfl_down(ssum, off, 64);
    if (lane == 0) xxh[row] = -0.5f * ssum;
}

// ---------------------------------------------------------------------------
// fp8 GEMM, Mt=Nt=256, 8 waves at Mw=128 x Nw=64 (rho = LDS/MFMA ~ 1.4),
// BK = 128 bytes, dbuf 128 KiB LDS. DRAIN-style sync (R4-proven, robust to
// compiler-inserted vmem): prefetch A/B(t+1) -> buf^1 at tile top, 4-phase
// snake compute with setprio, single WAITVM(0)+BAR at tile end. No counted
// vmcnt, no staging into a live buffer. T1 XCD swizzle, T2 slot swizzle.
// C = 4*(A8*B8^T) + xxh[row] + mmh[col]
// ---------------------------------------------------------------------------
#define BKB 128
#define TILEB (256 * BKB)              // 32 KiB per matrix per buffer

__global__ __launch_bounds__(512, 2) void gemm_ep(
    const unsigned char* __restrict__ A8, const unsigned char* __restrict__ B8,
    const float* __restrict__ xxh, const float* __restrict__ mmh,
    float* __restrict__ C) {
    __shared__ unsigned char Als[2 * TILEB];   // 64 KiB
    __shared__ unsigned char Bls[2 * TILEB];   // 64 KiB

    int t = threadIdx.x;
    int lane = t & 63;
    int wave = t >> 6;
    int wr = wave >> 2;          // 0..1 (M half: 128 rows)
    int wc = wave & 3;           // 0..3 (N quarter: 64 rows)
    int r  = lane & 15;
    int lk = lane >> 4;          // k-slot 0..3 (32B each)

    // T1: XCD swizzle, nwg=256 = 8 XCDs x 32 (bijective)
    int bid = blockIdx.x;
    int s = (bid & 7) * 32 + (bid >> 3);
    int tm = s >> 6;             // 0..3   (M/256)
    int tn = s & 63;             // 0..63  (N/256)

    const unsigned char* Abase = A8 + (size_t)tn * 256 * K;
    const unsigned char* Bbase = B8 + (size_t)tm * 256 * K;

    f32x4 acc[8][4] = {};
    i32x8 af[4];                 // current m-half: 4 mi fragments
    i32x8 bf[2];                 // current n-half: 2 ni fragments

    // stage one 256x128B matrix tile: 2048 16B chunks, 4 per thread.
    // lds row=c>>3, slot=c&7; SOURCE slot pre-swizzled ^(row&7) (rule 21).
#define STAGE_MAT(Gb_, Lb_, kt_)                                               \
    {                                                                          \
        const unsigned char* g_ = (Gb_) + (size_t)(kt_) * BKB;                 \
        unsigned char* l_ = (Lb_);                                             \
        _Pragma("unroll")                                                      \
        for (int i_ = 0; i_ < 4; ++i_) {                                       \
            int c_ = i_ * 512 + t;                                             \
            int row_ = c_ >> 3;                                                \
            int slot_ = (c_ & 7) ^ (row_ & 7);                                 \
            gload_lds16(g_ + (size_t)row_ * K + slot_ * 16,                    \
                        l_ + (i_ * 512 + (wave << 6)) * 16);                   \
        }                                                                      \
    }

    // fragment: 32B of row at k-slot lk; swizzled byte slots (2lk|h)^(r&7)
#define LOAD_AF(As_, mh_)                                                      \
    _Pragma("unroll")                                                          \
    for (int mi_ = 0; mi_ < 4; ++mi_) {                                        \
        int row_ = wr * 128 + (mh_) * 64 + mi_ * 16 + r;                       \
        uint4 q0_ = *(const uint4*)&(As_)[(row_ << 7) +                        \
                                          ((((lk << 1) | 0) ^ (r & 7)) << 4)]; \
        uint4 q1_ = *(const uint4*)&(As_)[(row_ << 7) +                        \
                                          ((((lk << 1) | 1) ^ (r & 7)) << 4)]; \
        af[mi_][0] = q0_.x; af[mi_][1] = q0_.y;                                \
        af[mi_][2] = q0_.z; af[mi_][3] = q0_.w;                                \
        af[mi_][4] = q1_.x; af[mi_][5] = q1_.y;                                \
        af[mi_][6] = q1_.z; af[mi_][7] = q1_.w;                                \
    }

#define LOAD_BF(Bs_, nh_)                                                      \
    _Pragma("unroll")                                                          \
    for (int ni_ = 0; ni_ < 2; ++ni_) {                                        \
        int row_ = wc * 64 + (nh_) * 32 + ni_ * 16 + r;                        \
        uint4 q0_ = *(const uint4*)&(Bs_)[(row_ << 7) +                        \
                                          ((((lk << 1) | 0) ^ (r & 7)) << 4)]; \
        uint4 q1_ = *(const uint4*)&(Bs_)[(row_ << 7) +                        \
                                          ((((lk << 1) | 1) ^ (r & 7)) << 4)]; \
        bf[ni_][0] = q0_.x; bf[ni_][1] = q0_.y;                                \
        bf[ni_][2] = q0_.z; bf[ni_][3] = q0_.w;                                \
        bf[ni_][4] = q1_.x; bf[ni_][5] = q1_.y;                                \
        bf[ni_][6] = q1_.z; bf[ni_][7] = q1_.w;                                \
    }

#define MFMA_Q(mh_, nh_)                                                       \
    __builtin_amdgcn_s_setprio(1);                                             \
    _Pragma("unroll")                                                          \
    for (int mi_ = 0; mi_ < 4; ++mi_)                                          \
        _Pragma("unroll")                                                      \
        for (int ni_ = 0; ni_ < 2; ++ni_)                                      \
            acc[(mh_) * 4 + mi_][(nh_) * 2 + ni_] =                            \
                __builtin_amdgcn_mfma_scale_f32_16x16x128_f8f6f4(              \
                    af[mi_], bf[ni_],                                          \
                    acc[(mh_) * 4 + mi_][(nh_) * 2 + ni_],                     \
                    0, 0,                   /* cbsz=FP8, blgp=FP8 */           \
                    0, 0x7f7f7f7f,          /* scale_a = 1.0 */                \
                    0, 0x7f7f7f7f);         /* scale_b = 1.0 */                \
    __builtin_amdgcn_s_setprio(0);

    // ---- prologue: A(0),B(0) -> buf0; drain; barrier.
    STAGE_MAT(Abase, Als, 0);
    STAGE_MAT(Bbase, Bls, 0);
    WAITVM(0);
    BAR();

    const int NT = K / BKB;           // 8 K-tiles
    for (int kt = 0; kt < NT; ++kt) {
        int cur = kt & 1;
        const unsigned char* As = Als + cur * TILEB;
        const unsigned char* Bs = Bls + cur * TILEB;

        // prefetch next tile into the other buffer (in flight over all 4 phases)
        if (kt + 1 < NT) {
            STAGE_MAT(Abase, Als + (cur ^ 1) * TILEB, kt + 1);
            STAGE_MAT(Bbase, Bls + (cur ^ 1) * TILEB, kt + 1);
        }

        // ---- phase 1: (m0, n0)
        LOAD_AF(As, 0);
        LOAD_BF(Bs, 0);
        BAR();
        MFMA_Q(0, 0);
        BAR();

        // ---- phase 2: (m0, n1)
        LOAD_BF(Bs, 1);
        BAR();
        MFMA_Q(0, 1);
        BAR();

        // ---- phase 3: (m1, n1)
        LOAD_AF(As, 1);
        BAR();
        MFMA_Q(1, 1);
        BAR();

        // ---- phase 4: (m1, n0)
        LOAD_BF(Bs, 0);
        BAR();
        MFMA_Q(1, 0);
        // drain prefetch (robust: retires ALL vmem incl. any compiler-inserted)
        if (kt + 1 < NT) WAITVM(0);
        BAR();
    }

    // epilogue: C[row][col] = 4*acc + xxh[row] + mmh[col]
    int rowb = tn * 256 + wr * 128;
    int colb = tm * 256 + wc * 64;
#pragma unroll
    for (int mi = 0; mi < 8; ++mi) {
        float xh[4];
#pragma unroll
        for (int j = 0; j < 4; ++j) xh[j] = xxh[rowb + mi * 16 + lk * 4 + j];
#pragma unroll
        for (int ni = 0; ni < 4; ++ni) {
            int col = colb + ni * 16 + r;
            float mh = mmh[col];
#pragma unroll
            for (int j = 0; j < 4; ++j) {
                int row = rowb + mi * 16 + lk * 4 + j;
                C[(size_t)row * M + col] = acc[mi][ni][j] * 4.0f + xh[j] + mh;
            }
        }
    }
#undef STAGE_MAT
#undef LOAD_AF
#undef LOAD_BF
#undef MFMA_Q
}

extern "C" void kernel_launch(void* const* d_in, const int* in_sizes, int n_in,
                              void* d_out, int out_size, void* d_ws, size_t ws_size,
                              hipStream_t stream) {
    const float* x    = (const float*)d_in[0];
    const float* mu   = (const float*)d_in[1];
    const float* stdv = (const float*)d_in[2];
    float* out = (float*)d_out;

    char* ws = (char*)d_ws;
    unsigned char* xb8 = (unsigned char*)ws;                        // N*K   = 16 MB
    unsigned char* Wb8 = (unsigned char*)(ws + (size_t)N * K);      // M*K   = 1 MB
    float* xxh = (float*)(ws + (size_t)N * K + (size_t)M * K);      // 64 KB
    float* mmh = (float*)((char*)xxh + (size_t)N * sizeof(float));  // 4 KB

    prep_mu<<<M, 256, 0, stream>>>(mu, stdv, (uint32*)Wb8, mmh);
    prep_x<<<N / 4, 256, 0, stream>>>(x, stdv, (uint32*)xb8, xxh);
    gemm_ep<<<(N / 256) * (M / 256), 512, 0, stream>>>(xb8, Wb8, xxh, mmh, out);
}